// Round 25
// baseline (122.564 us; speedup 1.0000x reference)
//
#include <hip/hip_runtime.h>

#define N_NODES 20000
#define N_EDGES 320000
#define IN_F 256
#define EIN_F 64
#define NH 4
#define HFE 64   // H*FE
#define HFO 256  // H*FO
#define NCOL 384 // 64+64+256 fused output cols
#define SLOTS 64 // padded-CSR slots per node

typedef __attribute__((ext_vector_type(8))) short short8;   // 8 bf16 (4 VGPRs)
typedef __attribute__((ext_vector_type(4))) float f32x4;

__device__ inline short f2bf(float f) {
    unsigned u = __builtin_bit_cast(unsigned, f);
    unsigned r = (u + 0x7FFFu + ((u >> 16) & 1u)) >> 16;
    return (short)r;
}
__device__ inline float bf2f(unsigned short u) {
    unsigned v = ((unsigned)u) << 16;
    return __builtin_bit_cast(float, v);
}

// ---------------- K0: pack weights into bf16 fragment order (400 blocks) ----------------
__global__ void k_pack(const float* __restrict__ Wni, const float* __restrict__ Wnj,
                       const float* __restrict__ Wsrc, const float* __restrict__ Wfij,
                       short* __restrict__ wpack, short* __restrict__ wfpack) {
    int idx = blockIdx.x * 256 + threadIdx.x;
    if (idx < IN_F * NCOL) {
        int k = idx / NCOL, col = idx % NCOL;
        float v;
        if (col < 64)        v = Wni[k * 64 + col];
        else if (col < 128)  v = Wnj[k * 64 + (col - 64)];
        else                 v = Wsrc[k * 256 + (col - 128)];
        int kb = k >> 5, ct = col >> 4, g = (k >> 3) & 3, i = k & 7, l15 = col & 15;
        wpack[(((kb * 24 + ct) * 64) + g * 16 + l15) * 8 + i] = f2bf(v);
    } else if (idx < IN_F * NCOL + EIN_F * 64) {
        int j = idx - IN_F * NCOL;
        int k = j >> 6, col = j & 63;
        int kb = k >> 5, ct = col >> 4, g = (k >> 3) & 3, i = k & 7, l15 = col & 15;
        wfpack[(((kb * 4 + ct) * 64) + g * 16 + l15) * 8 + i] = f2bf(Wfij[k * 64 + col]);
    }
}

// ---------------- K1: node GEMM via MFMA (16 rows/block); also zeros cur ----------------
__global__ __launch_bounds__(256) void k1_mfma(
    const float* __restrict__ x, const short* __restrict__ wpack,
    short* __restrict__ xni_b, short* __restrict__ xnj_b, short* __restrict__ hfeat_b,
    int* __restrict__ cur)
{
    const int tid  = threadIdx.x;
    const int w    = tid >> 6;
    const int lane = tid & 63;
    const int l15  = lane & 15;
    const int g    = lane >> 4;

    const int r0 = blockIdx.x * 16;
    if (tid < 16) cur[r0 + tid] = 0;     // slot counters for k2

    f32x4 acc[6];
#pragma unroll
    for (int j = 0; j < 6; j++) acc[j] = (f32x4){0.f, 0.f, 0.f, 0.f};

    const short8* bp = (const short8*)wpack;
    const float* xrow = x + (size_t)(r0 + l15) * 256;

    for (int kb = 0; kb < 8; kb++) {
        const float* ap = xrow + kb * 32 + 8 * g;
        float4 a0 = *(const float4*)ap;
        float4 a1 = *(const float4*)(ap + 4);
        short8 afr;
        afr[0] = f2bf(a0.x); afr[1] = f2bf(a0.y); afr[2] = f2bf(a0.z); afr[3] = f2bf(a0.w);
        afr[4] = f2bf(a1.x); afr[5] = f2bf(a1.y); afr[6] = f2bf(a1.z); afr[7] = f2bf(a1.w);
        const short8* bkb = bp + (size_t)kb * 24 * 64 + lane;
#pragma unroll
        for (int j = 0; j < 6; j++)
            acc[j] = __builtin_amdgcn_mfma_f32_16x16x32_bf16(afr, bkb[(w * 6 + j) * 64], acc[j], 0, 0, 0);
    }

    const int rowb = r0 + 4 * g;
#pragma unroll
    for (int j = 0; j < 6; j++) {
        const int col = (w * 6 + j) * 16 + l15;
#pragma unroll
        for (int reg = 0; reg < 4; reg++) {
            const int row = rowb + reg;
            if (col < 64)        xni_b[(size_t)row * 64 + col] = f2bf(acc[j][reg]);
            else if (col < 128)  xnj_b[(size_t)row * 64 + (col - 64)] = f2bf(acc[j][reg]);
            else                 hfeat_b[(size_t)row * 256 + (col - 128)] = f2bf(acc[j][reg]);
        }
    }
}

// ---------------- K2: edge scores; 16 B packed slot {bf16 ex[4], sv} single store ----------
__global__ __launch_bounds__(256) void k2_edge_mfma(
    const float* __restrict__ efeats, const int* __restrict__ src, const int* __restrict__ dst,
    const short* __restrict__ wfpack, const float* __restrict__ attn,
    const float* __restrict__ bias,
    const short* __restrict__ xni_b, const short* __restrict__ xnj_b,
    float* __restrict__ fout, unsigned* __restrict__ slotb, int* __restrict__ cur)
{
    const int tid  = threadIdx.x;
    const int w    = tid >> 6;
    const int lane = tid & 63;
    const int l15  = lane & 15;
    const int g    = lane >> 4;             // 0..3

    float4 bias4[4], attn4[4];
#pragma unroll
    for (int ct = 0; ct < 4; ct++) {
        bias4[ct] = *(const float4*)(bias + ct * 16 + 4 * g);
        attn4[ct] = *(const float4*)(attn + ct * 16 + 4 * g);
    }

    short8 bfr[2][4];
    const short8* wf = (const short8*)wfpack;
#pragma unroll
    for (int kb = 0; kb < 2; kb++)
#pragma unroll
        for (int ct = 0; ct < 4; ct++)
            bfr[kb][ct] = wf[(kb * 4 + ct) * 64 + lane];

    const int nwaves = gridDim.x * 4;
    const int gwid = blockIdx.x * 4 + w;
    const int ngroups = N_EDGES / 16;       // 20000

    for (int grp = gwid; grp < ngroups; grp += nwaves) {
        const int e0 = grp * 16;
        const int e  = e0 + l15;            // this lane's edge

        const int sv = src[e];
        const int dv = dst[e];

        // issue gathers early; they overlap the MFMA block below
        ushort4 xgv[4], ygv[4];
#pragma unroll
        for (int ct = 0; ct < 4; ct++) {
            xgv[ct] = *(const ushort4*)(xni_b + (size_t)sv * 64 + ct * 16 + 4 * g);
            ygv[ct] = *(const ushort4*)(xnj_b + (size_t)dv * 64 + ct * 16 + 4 * g);
        }

        f32x4 c[4];
#pragma unroll
        for (int ct = 0; ct < 4; ct++) c[ct] = (f32x4){0.f, 0.f, 0.f, 0.f};

#pragma unroll
        for (int kb = 0; kb < 2; kb++) {
            const float* ap = efeats + (size_t)e * 64 + kb * 32 + 8 * g;
            float4 a0 = *(const float4*)ap;
            float4 a1 = *(const float4*)(ap + 4);
            short8 afr;
            afr[0] = f2bf(a0.x); afr[1] = f2bf(a0.y); afr[2] = f2bf(a0.z); afr[3] = f2bf(a0.w);
            afr[4] = f2bf(a1.x); afr[5] = f2bf(a1.y); afr[6] = f2bf(a1.z); afr[7] = f2bf(a1.w);
#pragma unroll
            for (int ct = 0; ct < 4; ct++)
                c[ct] = __builtin_amdgcn_mfma_f32_16x16x32_bf16(bfr[kb][ct], afr, c[ct], 0, 0, 0);
        }

        float p[4];
#pragma unroll
        for (int ct = 0; ct < 4; ct++) {
            float4 f4;
            f4.x = c[ct][0] + bf2f(xgv[ct].x) + bf2f(ygv[ct].x) + bias4[ct].x;
            f4.y = c[ct][1] + bf2f(xgv[ct].y) + bf2f(ygv[ct].y) + bias4[ct].y;
            f4.z = c[ct][2] + bf2f(xgv[ct].z) + bf2f(ygv[ct].z) + bias4[ct].z;
            f4.w = c[ct][3] + bf2f(xgv[ct].w) + bf2f(ygv[ct].w) + bias4[ct].w;
            f4.x = (f4.x >= 0.f) ? f4.x : 0.2f * f4.x;
            f4.y = (f4.y >= 0.f) ? f4.y : 0.2f * f4.y;
            f4.z = (f4.z >= 0.f) ? f4.z : 0.2f * f4.z;
            f4.w = (f4.w >= 0.f) ? f4.w : 0.2f * f4.w;
            *(float4*)(fout + (size_t)e * 64 + ct * 16 + 4 * g) = f4;
            p[ct] = f4.x * attn4[ct].x + f4.y * attn4[ct].y
                  + f4.z * attn4[ct].z + f4.w * attn4[ct].w;
        }

#pragma unroll
        for (int ct = 0; ct < 4; ct++) {
            p[ct] += __shfl_xor(p[ct], 16, 64);
            p[ct] += __shfl_xor(p[ct], 32, 64);
        }

        if (g == 0) {
            const float ex0 = __expf(p[0]), ex1 = __expf(p[1]),
                        ex2 = __expf(p[2]), ex3 = __expf(p[3]);
            const unsigned w0 = (unsigned)(unsigned short)f2bf(ex0)
                              | ((unsigned)(unsigned short)f2bf(ex1) << 16);
            const unsigned w1 = (unsigned)(unsigned short)f2bf(ex2)
                              | ((unsigned)(unsigned short)f2bf(ex3) << 16);
            const int pos = atomicAdd(&cur[dv], 1);
            const size_t slot = ((size_t)dv << 6) + pos;
            uint4 sval = {w0, w1, (unsigned)sv, 0u};
            *(uint4*)(slotb + slot * 4) = sval;
        }
    }
}

// ---------------- K5: gather per dst node; slots staged cooperatively in LDS ----------
__global__ __launch_bounds__(256) void k5_gather(
    const int* __restrict__ cur, const unsigned* __restrict__ slotb,
    const short* __restrict__ hfeat_b, const float* __restrict__ x,
    float* __restrict__ out)
{
    __shared__ uint4 slds[4][SLOTS];
    const int w = threadIdx.x >> 6, lane = threadIdx.x & 63;
    const int d = blockIdx.x * 4 + w;
    if (d >= N_NODES) return;
    const int deg = cur[d];
    const int h = lane >> 4;
    const int s0 = d << 6;                  // slot base
    const bool hi = (h >= 2);

    // cooperative stage: lane i loads slot i (coalesced, parallel across lanes)
    if (lane < deg)
        slds[w][lane] = *(const uint4*)(slotb + (size_t)(s0 + lane) * 4);

    const size_t ob = (size_t)d * 256 + lane * 4;
    const float4 xr = *(const float4*)(x + ob);
    if (deg == 0) {
        *(float4*)(out + ob) = xr;
        return;
    }

    float a0 = 0.f, a1 = 0.f, a2 = 0.f, a3 = 0.f, dsum = 0.f;
    for (int base = 0; base < deg; base += 8) {
        const int m = deg - base;
        int sj[8]; unsigned ww[8]; ushort4 hv[8];
#pragma unroll
        for (int j = 0; j < 8; j++) if (j < m) {
            const uint4 s = slds[w][base + j];   // broadcast LDS read
            ww[j] = hi ? s.y : s.x;
            sj[j] = (int)s.z;
        }
#pragma unroll
        for (int j = 0; j < 8; j++) if (j < m)
            hv[j] = *(const ushort4*)(hfeat_b + (size_t)sj[j] * 256 + lane * 4);
#pragma unroll
        for (int j = 0; j < 8; j++) if (j < m) {
            const unsigned short us = (h & 1) ? (unsigned short)(ww[j] >> 16)
                                              : (unsigned short)(ww[j] & 0xffffu);
            const float s = bf2f(us);
            dsum += s;
            a0 += s * bf2f(hv[j].x);
            a1 += s * bf2f(hv[j].y);
            a2 += s * bf2f(hv[j].z);
            a3 += s * bf2f(hv[j].w);
        }
    }

    const float inv = 1.f / dsum;
    float4 o = {xr.x + a0 * inv, xr.y + a1 * inv, xr.z + a2 * inv, xr.w + a3 * inv};
    *(float4*)(out + ob) = o;
}

extern "C" void kernel_launch(void* const* d_in, const int* in_sizes, int n_in,
                              void* d_out, int out_size, void* d_ws, size_t ws_size,
                              hipStream_t stream) {
    const float* x      = (const float*)d_in[0];
    const float* efeats = (const float*)d_in[1];
    const int*   src    = (const int*)d_in[2];
    const int*   dst    = (const int*)d_in[3];
    const float* Wni    = (const float*)d_in[4];
    const float* Wfij   = (const float*)d_in[5];
    const float* Wnj    = (const float*)d_in[6];
    const float* Wsrc   = (const float*)d_in[7];
    const float* attn   = (const float*)d_in[8];
    const float* bias   = (const float*)d_in[9];

    float* out  = (float*)d_out;                      // [N, 256]
    float* fout = out + (size_t)N_NODES * HFO;        // [E, 64]

    float*    ws     = (float*)d_ws;
    unsigned* slotb  = (unsigned*)ws;                            // N*SLOTS*4 u32 (20.5 MB)
    int*      cur    = (int*)(slotb + (size_t)N_NODES * SLOTS * 4); // N
    short*    xni_b  = (short*)(cur + N_NODES);                  // N*64 bf16
    short*    xnj_b  = xni_b + (size_t)N_NODES * 64;             // N*64 bf16
    short*    hfeat_b= xnj_b + (size_t)N_NODES * 64;             // N*256 bf16
    short*    wpack  = hfeat_b + (size_t)N_NODES * 256;          // 256*384 bf16
    short*    wfpack = wpack + (size_t)IN_F * NCOL;              // 64*64 bf16

    k_pack<<<400, 256, 0, stream>>>(Wni, Wnj, Wsrc, Wfij, wpack, wfpack);
    k1_mfma<<<N_NODES / 16, 256, 0, stream>>>(x, wpack, xni_b, xnj_b, hfeat_b, cur);
    k2_edge_mfma<<<960, 256, 0, stream>>>(efeats, src, dst, wfpack, attn, bias,
                                          xni_b, xnj_b, fout, slotb, cur);
    k5_gather<<<(N_NODES + 3) / 4, 256, 0, stream>>>(cur, slotb, hfeat_b, x, out);
}

// Round 26
// 119.780 us; speedup vs baseline: 1.0232x; 1.0232x over previous
//
#include <hip/hip_runtime.h>

#define N_NODES 20000
#define N_EDGES 320000
#define IN_F 256
#define EIN_F 64
#define NH 4
#define HFE 64   // H*FE
#define HFO 256  // H*FO
#define NCOL 384 // 64+64+256 fused output cols
#define SLOTS 64 // padded-CSR slots per node

typedef __attribute__((ext_vector_type(8))) short short8;   // 8 bf16 (4 VGPRs)
typedef __attribute__((ext_vector_type(4))) float f32x4;

__device__ inline short f2bf(float f) {
    unsigned u = __builtin_bit_cast(unsigned, f);
    unsigned r = (u + 0x7FFFu + ((u >> 16) & 1u)) >> 16;
    return (short)r;
}
__device__ inline float bf2f(unsigned short u) {
    unsigned v = ((unsigned)u) << 16;
    return __builtin_bit_cast(float, v);
}

// ---------------- K0: pack weights into bf16 fragment order (400 blocks) ----------------
__global__ void k_pack(const float* __restrict__ Wni, const float* __restrict__ Wnj,
                       const float* __restrict__ Wsrc, const float* __restrict__ Wfij,
                       short* __restrict__ wpack, short* __restrict__ wfpack) {
    int idx = blockIdx.x * 256 + threadIdx.x;
    if (idx < IN_F * NCOL) {
        int k = idx / NCOL, col = idx % NCOL;
        float v;
        if (col < 64)        v = Wni[k * 64 + col];
        else if (col < 128)  v = Wnj[k * 64 + (col - 64)];
        else                 v = Wsrc[k * 256 + (col - 128)];
        int kb = k >> 5, ct = col >> 4, g = (k >> 3) & 3, i = k & 7, l15 = col & 15;
        wpack[(((kb * 24 + ct) * 64) + g * 16 + l15) * 8 + i] = f2bf(v);
    } else if (idx < IN_F * NCOL + EIN_F * 64) {
        int j = idx - IN_F * NCOL;
        int k = j >> 6, col = j & 63;
        int kb = k >> 5, ct = col >> 4, g = (k >> 3) & 3, i = k & 7, l15 = col & 15;
        wfpack[(((kb * 4 + ct) * 64) + g * 16 + l15) * 8 + i] = f2bf(Wfij[k * 64 + col]);
    }
}

// ---------------- K1: node GEMM via MFMA (16 rows/block); also zeros cur ----------------
__global__ __launch_bounds__(256) void k1_mfma(
    const float* __restrict__ x, const short* __restrict__ wpack,
    short* __restrict__ xni_b, short* __restrict__ xnj_b, short* __restrict__ hfeat_b,
    int* __restrict__ cur)
{
    const int tid  = threadIdx.x;
    const int w    = tid >> 6;
    const int lane = tid & 63;
    const int l15  = lane & 15;
    const int g    = lane >> 4;

    const int r0 = blockIdx.x * 16;
    if (tid < 16) cur[r0 + tid] = 0;     // slot counters for k2

    f32x4 acc[6];
#pragma unroll
    for (int j = 0; j < 6; j++) acc[j] = (f32x4){0.f, 0.f, 0.f, 0.f};

    const short8* bp = (const short8*)wpack;
    const float* xrow = x + (size_t)(r0 + l15) * 256;

    for (int kb = 0; kb < 8; kb++) {
        const float* ap = xrow + kb * 32 + 8 * g;
        float4 a0 = *(const float4*)ap;
        float4 a1 = *(const float4*)(ap + 4);
        short8 afr;
        afr[0] = f2bf(a0.x); afr[1] = f2bf(a0.y); afr[2] = f2bf(a0.z); afr[3] = f2bf(a0.w);
        afr[4] = f2bf(a1.x); afr[5] = f2bf(a1.y); afr[6] = f2bf(a1.z); afr[7] = f2bf(a1.w);
        const short8* bkb = bp + (size_t)kb * 24 * 64 + lane;
#pragma unroll
        for (int j = 0; j < 6; j++)
            acc[j] = __builtin_amdgcn_mfma_f32_16x16x32_bf16(afr, bkb[(w * 6 + j) * 64], acc[j], 0, 0, 0);
    }

    const int rowb = r0 + 4 * g;
#pragma unroll
    for (int j = 0; j < 6; j++) {
        const int col = (w * 6 + j) * 16 + l15;
#pragma unroll
        for (int reg = 0; reg < 4; reg++) {
            const int row = rowb + reg;
            if (col < 64)        xni_b[(size_t)row * 64 + col] = f2bf(acc[j][reg]);
            else if (col < 128)  xnj_b[(size_t)row * 64 + (col - 64)] = f2bf(acc[j][reg]);
            else                 hfeat_b[(size_t)row * 256 + (col - 128)] = f2bf(acc[j][reg]);
        }
    }
}

// ---------------- K2: edge scores; 16 B packed slot {bf16 ex[4], sv} single store ----------
__global__ __launch_bounds__(256) void k2_edge_mfma(
    const float* __restrict__ efeats, const int* __restrict__ src, const int* __restrict__ dst,
    const short* __restrict__ wfpack, const float* __restrict__ attn,
    const float* __restrict__ bias,
    const short* __restrict__ xni_b, const short* __restrict__ xnj_b,
    float* __restrict__ fout, unsigned* __restrict__ slotb, int* __restrict__ cur)
{
    const int tid  = threadIdx.x;
    const int w    = tid >> 6;
    const int lane = tid & 63;
    const int l15  = lane & 15;
    const int g    = lane >> 4;             // 0..3

    float4 bias4[4], attn4[4];
#pragma unroll
    for (int ct = 0; ct < 4; ct++) {
        bias4[ct] = *(const float4*)(bias + ct * 16 + 4 * g);
        attn4[ct] = *(const float4*)(attn + ct * 16 + 4 * g);
    }

    short8 bfr[2][4];
    const short8* wf = (const short8*)wfpack;
#pragma unroll
    for (int kb = 0; kb < 2; kb++)
#pragma unroll
        for (int ct = 0; ct < 4; ct++)
            bfr[kb][ct] = wf[(kb * 4 + ct) * 64 + lane];

    const int nwaves = gridDim.x * 4;
    const int gwid = blockIdx.x * 4 + w;
    const int ngroups = N_EDGES / 16;       // 20000

    for (int grp = gwid; grp < ngroups; grp += nwaves) {
        const int e0 = grp * 16;
        const int e  = e0 + l15;            // this lane's edge

        const int sv = src[e];
        const int dv = dst[e];

        // issue gathers early; they overlap the MFMA block below
        ushort4 xgv[4], ygv[4];
#pragma unroll
        for (int ct = 0; ct < 4; ct++) {
            xgv[ct] = *(const ushort4*)(xni_b + (size_t)sv * 64 + ct * 16 + 4 * g);
            ygv[ct] = *(const ushort4*)(xnj_b + (size_t)dv * 64 + ct * 16 + 4 * g);
        }

        f32x4 c[4];
#pragma unroll
        for (int ct = 0; ct < 4; ct++) c[ct] = (f32x4){0.f, 0.f, 0.f, 0.f};

#pragma unroll
        for (int kb = 0; kb < 2; kb++) {
            const float* ap = efeats + (size_t)e * 64 + kb * 32 + 8 * g;
            float4 a0 = *(const float4*)ap;
            float4 a1 = *(const float4*)(ap + 4);
            short8 afr;
            afr[0] = f2bf(a0.x); afr[1] = f2bf(a0.y); afr[2] = f2bf(a0.z); afr[3] = f2bf(a0.w);
            afr[4] = f2bf(a1.x); afr[5] = f2bf(a1.y); afr[6] = f2bf(a1.z); afr[7] = f2bf(a1.w);
#pragma unroll
            for (int ct = 0; ct < 4; ct++)
                c[ct] = __builtin_amdgcn_mfma_f32_16x16x32_bf16(bfr[kb][ct], afr, c[ct], 0, 0, 0);
        }

        float p[4];
#pragma unroll
        for (int ct = 0; ct < 4; ct++) {
            float4 f4;
            f4.x = c[ct][0] + bf2f(xgv[ct].x) + bf2f(ygv[ct].x) + bias4[ct].x;
            f4.y = c[ct][1] + bf2f(xgv[ct].y) + bf2f(ygv[ct].y) + bias4[ct].y;
            f4.z = c[ct][2] + bf2f(xgv[ct].z) + bf2f(ygv[ct].z) + bias4[ct].z;
            f4.w = c[ct][3] + bf2f(xgv[ct].w) + bf2f(ygv[ct].w) + bias4[ct].w;
            f4.x = (f4.x >= 0.f) ? f4.x : 0.2f * f4.x;
            f4.y = (f4.y >= 0.f) ? f4.y : 0.2f * f4.y;
            f4.z = (f4.z >= 0.f) ? f4.z : 0.2f * f4.z;
            f4.w = (f4.w >= 0.f) ? f4.w : 0.2f * f4.w;
            *(float4*)(fout + (size_t)e * 64 + ct * 16 + 4 * g) = f4;
            p[ct] = f4.x * attn4[ct].x + f4.y * attn4[ct].y
                  + f4.z * attn4[ct].z + f4.w * attn4[ct].w;
        }

#pragma unroll
        for (int ct = 0; ct < 4; ct++) {
            p[ct] += __shfl_xor(p[ct], 16, 64);
            p[ct] += __shfl_xor(p[ct], 32, 64);
        }

        if (g == 0) {
            const float ex0 = __expf(p[0]), ex1 = __expf(p[1]),
                        ex2 = __expf(p[2]), ex3 = __expf(p[3]);
            const unsigned w0 = (unsigned)(unsigned short)f2bf(ex0)
                              | ((unsigned)(unsigned short)f2bf(ex1) << 16);
            const unsigned w1 = (unsigned)(unsigned short)f2bf(ex2)
                              | ((unsigned)(unsigned short)f2bf(ex3) << 16);
            const int pos = atomicAdd(&cur[dv], 1);
            const size_t slot = ((size_t)dv << 6) + pos;
            uint4 sval = {w0, w1, (unsigned)sv, 0u};
            *(uint4*)(slotb + slot * 4) = sval;
        }
    }
}

// ---------------- K5: gather per dst node; slots staged cooperatively in LDS ----------
__global__ __launch_bounds__(256) void k5_gather(
    const int* __restrict__ cur, const unsigned* __restrict__ slotb,
    const short* __restrict__ hfeat_b, const float* __restrict__ x,
    float* __restrict__ out)
{
    __shared__ uint4 slds[4][SLOTS];
    const int w = threadIdx.x >> 6, lane = threadIdx.x & 63;
    const int d = blockIdx.x * 4 + w;
    if (d >= N_NODES) return;
    const int deg = cur[d];
    const int h = lane >> 4;
    const int s0 = d << 6;                  // slot base
    const bool hi = (h >= 2);

    // cooperative stage: lane i loads slot i (coalesced, parallel across lanes)
    if (lane < deg)
        slds[w][lane] = *(const uint4*)(slotb + (size_t)(s0 + lane) * 4);

    const size_t ob = (size_t)d * 256 + lane * 4;
    const float4 xr = *(const float4*)(x + ob);
    if (deg == 0) {
        *(float4*)(out + ob) = xr;
        return;
    }

    float a0 = 0.f, a1 = 0.f, a2 = 0.f, a3 = 0.f, dsum = 0.f;
    for (int base = 0; base < deg; base += 8) {
        const int m = deg - base;
        int sj[8]; unsigned ww[8]; ushort4 hv[8];
#pragma unroll
        for (int j = 0; j < 8; j++) if (j < m) {
            const uint4 s = slds[w][base + j];   // broadcast LDS read
            ww[j] = hi ? s.y : s.x;
            sj[j] = (int)s.z;
        }
#pragma unroll
        for (int j = 0; j < 8; j++) if (j < m)
            hv[j] = *(const ushort4*)(hfeat_b + (size_t)sj[j] * 256 + lane * 4);
#pragma unroll
        for (int j = 0; j < 8; j++) if (j < m) {
            const unsigned short us = (h & 1) ? (unsigned short)(ww[j] >> 16)
                                              : (unsigned short)(ww[j] & 0xffffu);
            const float s = bf2f(us);
            dsum += s;
            a0 += s * bf2f(hv[j].x);
            a1 += s * bf2f(hv[j].y);
            a2 += s * bf2f(hv[j].z);
            a3 += s * bf2f(hv[j].w);
        }
    }

    const float inv = 1.f / dsum;
    float4 o = {xr.x + a0 * inv, xr.y + a1 * inv, xr.z + a2 * inv, xr.w + a3 * inv};
    *(float4*)(out + ob) = o;
}

extern "C" void kernel_launch(void* const* d_in, const int* in_sizes, int n_in,
                              void* d_out, int out_size, void* d_ws, size_t ws_size,
                              hipStream_t stream) {
    const float* x      = (const float*)d_in[0];
    const float* efeats = (const float*)d_in[1];
    const int*   src    = (const int*)d_in[2];
    const int*   dst    = (const int*)d_in[3];
    const float* Wni    = (const float*)d_in[4];
    const float* Wfij   = (const float*)d_in[5];
    const float* Wnj    = (const float*)d_in[6];
    const float* Wsrc   = (const float*)d_in[7];
    const float* attn   = (const float*)d_in[8];
    const float* bias   = (const float*)d_in[9];

    float* out  = (float*)d_out;                      // [N, 256]
    float* fout = out + (size_t)N_NODES * HFO;        // [E, 64]

    float*    ws     = (float*)d_ws;
    unsigned* slotb  = (unsigned*)ws;                            // N*SLOTS*4 u32 (20.5 MB)
    int*      cur    = (int*)(slotb + (size_t)N_NODES * SLOTS * 4); // N
    short*    xni_b  = (short*)(cur + N_NODES);                  // N*64 bf16
    short*    xnj_b  = xni_b + (size_t)N_NODES * 64;             // N*64 bf16
    short*    hfeat_b= xnj_b + (size_t)N_NODES * 64;             // N*256 bf16
    short*    wpack  = hfeat_b + (size_t)N_NODES * 256;          // 256*384 bf16
    short*    wfpack = wpack + (size_t)IN_F * NCOL;              // 64*64 bf16

    k_pack<<<400, 256, 0, stream>>>(Wni, Wnj, Wsrc, Wfij, wpack, wfpack);
    k1_mfma<<<N_NODES / 16, 256, 0, stream>>>(x, wpack, xni_b, xnj_b, hfeat_b, cur);
    k2_edge_mfma<<<640, 256, 0, stream>>>(efeats, src, dst, wfpack, attn, bias,
                                          xni_b, xnj_b, fout, slotb, cur);
    k5_gather<<<(N_NODES + 3) / 4, 256, 0, stream>>>(cur, slotb, hfeat_b, x, out);
}